// Round 3
// baseline (837.628 us; speedup 1.0000x reference)
//
#include <hip/hip_runtime.h>

// R3 theory: R1/R2 NaN = fp32 storage read as bf16 (reference declares float32;
// low half-words of floats are random-exponent "bf16" -> inf/NaN in softmax).
// Fix: runtime dtype detect + convert-all-inputs-to-bf16 pre-pass; dual-mode
// output store. Compute pipeline identical to R2 (twice-audited).

typedef unsigned short u16;
typedef __attribute__((ext_vector_type(8))) __bf16 bf16x8;
typedef __attribute__((ext_vector_type(4))) float f32x4;
typedef __attribute__((ext_vector_type(8))) unsigned short u16x8;

__device__ __forceinline__ float b2f(u16 u) {
    unsigned int i = ((unsigned int)u) << 16;
    float f; __builtin_memcpy(&f, &i, 4); return f;
}
__device__ __forceinline__ u16 f2b(float f) {
    unsigned int x; __builtin_memcpy(&x, &f, 4);
    x += 0x7fffu + ((x >> 16) & 1u);   // RTNE
    return (u16)(x >> 16);
}

#define LDT 72   // padded LDS row stride (bf16): 144B rows, 16B-aligned

// ---------------------------------------------------------------------------
// dtype detect: bf16 data -> max|v| ~ 3; fp32 data -> low half-words are
// mantissa noise with random exponents -> max huge. Write flag (1 = fp32).
// ---------------------------------------------------------------------------
__global__ void detect_dtype(const u16* __restrict__ x, int* __restrict__ flag)
{
    if (threadIdx.x == 0 && blockIdx.x == 0) {
        float mx = 0.f;
        for (int i = 0; i < 128; i++) {
            float v = fabsf(b2f(x[i]));
            if (!(v <= 1e30f)) v = 1e30f;     // inf/nan patterns count as huge
            mx = fmaxf(mx, v);
        }
        *flag = (mx > 1e4f) ? 1 : 0;
    }
}

// convert one array to bf16 (fp32 path) or copy (bf16 path), per flag
__global__ __launch_bounds__(256) void convert_in(
    const void* __restrict__ src, u16* __restrict__ dst, int n,
    const int* __restrict__ flag)
{
    const int fl = *flag;
    for (int i = blockIdx.x * 256 + threadIdx.x; i < n; i += gridDim.x * 256) {
        dst[i] = fl ? f2b(((const float*)src)[i]) : ((const u16*)src)[i];
    }
}

// ---------------------------------------------------------------------------
// K1: qkv GEMM (M=8192,N=2304,K=768, TN) + bias + 2D rope + k*0.125 + transpose
// -> qkvT[3][B*nH][L][hd] bf16. Rope pair partner (d^1) = adjacent lane.
// ---------------------------------------------------------------------------
__global__ __launch_bounds__(256) void gemm_qkv_rope(
    const u16* __restrict__ A, const u16* __restrict__ Bw,
    const u16* __restrict__ qb, u16* __restrict__ qkvT)
{
    __shared__ u16 lA[64 * LDT];
    __shared__ u16 lB[64 * LDT];
    const int tid = threadIdx.x;
    const int m0 = blockIdx.x * 64, n0 = blockIdx.y * 64;
    const int wave = tid >> 6, lane = tid & 63;
    const int wm = (wave & 1) * 32, wn = (wave >> 1) * 32;
    const int lm = lane & 15, lq = lane >> 4;
    f32x4 acc[2][2] = {};
    for (int k0 = 0; k0 < 768; k0 += 64) {
        if (k0) __syncthreads();
        #pragma unroll
        for (int s = tid; s < 512; s += 256) {
            const int row = s >> 3, kg = (s & 7) * 8;
            *(uint4*)&lA[row * LDT + kg] = *(const uint4*)(A + (size_t)(m0 + row) * 768 + k0 + kg);
            *(uint4*)&lB[row * LDT + kg] = *(const uint4*)(Bw + (size_t)(n0 + row) * 768 + k0 + kg);
        }
        __syncthreads();
        #pragma unroll
        for (int ks = 0; ks < 64; ks += 32) {
            bf16x8 a0 = *(const bf16x8*)&lA[(wm + lm) * LDT + ks + lq * 8];
            bf16x8 a1 = *(const bf16x8*)&lA[(wm + 16 + lm) * LDT + ks + lq * 8];
            bf16x8 b0 = *(const bf16x8*)&lB[(wn + lm) * LDT + ks + lq * 8];
            bf16x8 b1 = *(const bf16x8*)&lB[(wn + 16 + lm) * LDT + ks + lq * 8];
            acc[0][0] = __builtin_amdgcn_mfma_f32_16x16x32_bf16(a0, b0, acc[0][0], 0, 0, 0);
            acc[0][1] = __builtin_amdgcn_mfma_f32_16x16x32_bf16(a0, b1, acc[0][1], 0, 0, 0);
            acc[1][0] = __builtin_amdgcn_mfma_f32_16x16x32_bf16(a1, b0, acc[1][0], 0, 0, 0);
            acc[1][1] = __builtin_amdgcn_mfma_f32_16x16x32_bf16(a1, b1, acc[1][1], 0, 0, 0);
        }
    }
    const size_t HL = (size_t)96 * 1024 * 64;
    const int which = n0 / 768;
    const int nh = (n0 >> 6) % 12;
    #pragma unroll
    for (int i = 0; i < 2; i++)
        #pragma unroll
        for (int j = 0; j < 2; j++)
            #pragma unroll
            for (int r = 0; r < 4; r++) {
                const int m = m0 + wm + i * 16 + lq * 4 + r;
                const int d = wn + j * 16 + lm;
                float v = acc[i][j][r] + b2f(qb[n0 + d]);
                const float p = __shfl_xor(v, 1);
                const int l = m & 1023, bb = m >> 10;
                float o = v;
                if (which < 2) {
                    const int pi = d >> 1, jj = pi & 15;
                    const float coord = (pi < 16) ? (float)(l & 31) : (float)(l >> 5);
                    const float ang = coord * __expf(-(float)jj * 0.5756462732485115f);
                    float sn, cs; __sincosf(ang, &sn, &cs);
                    o = v * cs + ((d & 1) ? p * sn : -(p * sn));
                    if (which == 1) o *= 0.125f;
                }
                qkvT[(size_t)which * HL + ((size_t)(bb * 12 + nh) * 1024 + l) * 64 + d] = f2b(o);
            }
}

// ---------------------------------------------------------------------------
// K3: proj GEMM + bias; output fp32 or bf16 per flag
// ---------------------------------------------------------------------------
__global__ __launch_bounds__(256) void gemm_proj(
    const u16* __restrict__ A, const u16* __restrict__ Bw,
    const u16* __restrict__ bias, void* __restrict__ C,
    const int* __restrict__ flag)
{
    __shared__ u16 lA[64 * LDT];
    __shared__ u16 lB[64 * LDT];
    const int tid = threadIdx.x;
    const int m0 = blockIdx.x * 64, n0 = blockIdx.y * 64;
    const int wave = tid >> 6, lane = tid & 63;
    const int wm = (wave & 1) * 32, wn = (wave >> 1) * 32;
    const int lm = lane & 15, lq = lane >> 4;
    f32x4 acc[2][2] = {};
    for (int k0 = 0; k0 < 768; k0 += 64) {
        if (k0) __syncthreads();
        #pragma unroll
        for (int s = tid; s < 512; s += 256) {
            const int row = s >> 3, kg = (s & 7) * 8;
            *(uint4*)&lA[row * LDT + kg] = *(const uint4*)(A + (size_t)(m0 + row) * 768 + k0 + kg);
            *(uint4*)&lB[row * LDT + kg] = *(const uint4*)(Bw + (size_t)(n0 + row) * 768 + k0 + kg);
        }
        __syncthreads();
        #pragma unroll
        for (int ks = 0; ks < 64; ks += 32) {
            bf16x8 a0 = *(const bf16x8*)&lA[(wm + lm) * LDT + ks + lq * 8];
            bf16x8 a1 = *(const bf16x8*)&lA[(wm + 16 + lm) * LDT + ks + lq * 8];
            bf16x8 b0 = *(const bf16x8*)&lB[(wn + lm) * LDT + ks + lq * 8];
            bf16x8 b1 = *(const bf16x8*)&lB[(wn + 16 + lm) * LDT + ks + lq * 8];
            acc[0][0] = __builtin_amdgcn_mfma_f32_16x16x32_bf16(a0, b0, acc[0][0], 0, 0, 0);
            acc[0][1] = __builtin_amdgcn_mfma_f32_16x16x32_bf16(a0, b1, acc[0][1], 0, 0, 0);
            acc[1][0] = __builtin_amdgcn_mfma_f32_16x16x32_bf16(a1, b0, acc[1][0], 0, 0, 0);
            acc[1][1] = __builtin_amdgcn_mfma_f32_16x16x32_bf16(a1, b1, acc[1][1], 0, 0, 0);
        }
    }
    const int fl = *flag;
    #pragma unroll
    for (int i = 0; i < 2; i++)
        #pragma unroll
        for (int j = 0; j < 2; j++)
            #pragma unroll
            for (int r = 0; r < 4; r++) {
                const int m = m0 + wm + i * 16 + lq * 4 + r;
                const int n = n0 + wn + j * 16 + lm;
                const float v = acc[i][j][r] + b2f(bias[n]);
                if (fl) ((float*)C)[(size_t)m * 768 + n] = v;
                else    ((u16*)C)[(size_t)m * 768 + n] = f2b(v);
            }
}

// ---------------------------------------------------------------------------
// K2: flash attention (unchanged from R2, twice-audited)
// ---------------------------------------------------------------------------
__global__ __launch_bounds__(256) void flash_attn(
    const u16* __restrict__ qkvT, const u16* __restrict__ relH,
    const u16* __restrict__ relW, u16* __restrict__ outb)
{
    __shared__ float qps[64][68];
    __shared__ u16   ks2[64][72];
    __shared__ u16   vs2[64][72];
    __shared__ float rh[64][33];
    __shared__ float rw[64][33];
    const int tid = threadIdx.x;
    const int bn = blockIdx.x;
    const int q0 = blockIdx.y * 64;
    const size_t HL = (size_t)96 * 1024 * 64;
    const u16* qg  = qkvT + (size_t)bn * 1024 * 64 + (size_t)q0 * 64;
    const u16* kgb = qkvT + HL + (size_t)bn * 1024 * 64;
    const u16* vgb = kgb + HL;

    for (int g = tid; g < 1024; g += 256) {
        ushort4 u = ((const ushort4*)qg)[g];
        int r = g >> 4, c = (g & 15) * 4;
        qps[r][c] = b2f(u.x); qps[r][c + 1] = b2f(u.y);
        qps[r][c + 2] = b2f(u.z); qps[r][c + 3] = b2f(u.w);
    }
    __syncthreads();
    for (int o = tid; o < 2048; o += 256) {
        int qi = o >> 5, kk = o & 31;
        int ql = q0 + qi;
        const u16* Rh = relH + (size_t)((ql >> 5) - kk + 31) * 64;
        const u16* Rw = relW + (size_t)((ql & 31) - kk + 31) * 64;
        float ah = 0.f, aw = 0.f;
        for (int d = 0; d < 64; d++) {
            float qv = qps[qi][d];
            ah += qv * b2f(Rh[d]);
            aw += qv * b2f(Rw[d]);
        }
        rh[qi][kk] = ah; rw[qi][kk] = aw;
    }
    const int q = tid >> 2, g4 = tid & 3;
    float qreg[64];
    #pragma unroll
    for (int c = 0; c < 16; c++) {
        f32x4 t = *(const f32x4*)&qps[q][c * 4];
        qreg[c * 4] = t[0]; qreg[c * 4 + 1] = t[1];
        qreg[c * 4 + 2] = t[2]; qreg[c * 4 + 3] = t[3];
    }
    float m_run = -1e30f, l_run = 0.f;
    float accf[16];
    #pragma unroll
    for (int e = 0; e < 16; e++) accf[e] = 0.f;

    for (int kt = 0; kt < 16; kt++) {
        __syncthreads();
        const u16* kp = kgb + (size_t)kt * 64 * 64;
        const u16* vp = vgb + (size_t)kt * 64 * 64;
        for (int g = tid; g < 1024; g += 256) {
            int r = g >> 4, c = (g & 15) * 4;
            *(ushort4*)&ks2[r][c] = ((const ushort4*)kp)[g];
            *(ushort4*)&vs2[r][c] = ((const ushort4*)vp)[g];
        }
        __syncthreads();
        const float rh0 = rh[q][kt * 2], rh1 = rh[q][kt * 2 + 1];
        float sc[16];
        #pragma unroll
        for (int j = 0; j < 16; j++) {
            const int kj = g4 + j * 4;
            const u16x8* krow = (const u16x8*)&ks2[kj][0];
            float s = 0.f;
            #pragma unroll
            for (int c = 0; c < 8; c++) {
                u16x8 kv = krow[c];
                s += qreg[c * 8 + 0] * b2f(kv[0]) + qreg[c * 8 + 1] * b2f(kv[1])
                   + qreg[c * 8 + 2] * b2f(kv[2]) + qreg[c * 8 + 3] * b2f(kv[3])
                   + qreg[c * 8 + 4] * b2f(kv[4]) + qreg[c * 8 + 5] * b2f(kv[5])
                   + qreg[c * 8 + 6] * b2f(kv[6]) + qreg[c * 8 + 7] * b2f(kv[7]);
            }
            sc[j] = s + ((kj >> 5) ? rh1 : rh0) + rw[q][kj & 31];
        }
        float tmax = sc[0];
        #pragma unroll
        for (int j = 1; j < 16; j++) tmax = fmaxf(tmax, sc[j]);
        tmax = fmaxf(tmax, __shfl_xor(tmax, 1, 4));
        tmax = fmaxf(tmax, __shfl_xor(tmax, 2, 4));
        const float m_new = fmaxf(m_run, tmax);
        const float alpha = __expf(m_run - m_new);
        float lsum = 0.f;
        #pragma unroll
        for (int j = 0; j < 16; j++) { float pv = __expf(sc[j] - m_new); sc[j] = pv; lsum += pv; }
        lsum += __shfl_xor(lsum, 1, 4);
        lsum += __shfl_xor(lsum, 2, 4);
        m_run = m_new;
        l_run = l_run * alpha + lsum;
        #pragma unroll
        for (int e = 0; e < 16; e++) accf[e] *= alpha;
        #pragma unroll
        for (int j = 0; j < 16; j++) qps[q][g4 + j * 4] = sc[j];
        __syncthreads();
        #pragma unroll 4
        for (int k = 0; k < 64; k++) {
            const float pv = qps[q][k];
            const u16x8* vrow = (const u16x8*)&vs2[k][g4 * 16];
            u16x8 v0 = vrow[0], v1 = vrow[1];
            #pragma unroll
            for (int e = 0; e < 8; e++) {
                accf[e]     += pv * b2f(v0[e]);
                accf[8 + e] += pv * b2f(v1[e]);
            }
        }
    }
    const float rinv = 1.f / l_run;
    const int bb = bn / 12, nh = bn % 12;
    u16* op = outb + ((size_t)(bb * 1024 + q0 + q)) * 768 + nh * 64 + g4 * 16;
    #pragma unroll
    for (int c = 0; c < 4; c++) {
        ushort4 u;
        u.x = f2b(accf[c * 4 + 0] * rinv);
        u.y = f2b(accf[c * 4 + 1] * rinv);
        u.z = f2b(accf[c * 4 + 2] * rinv);
        u.w = f2b(accf[c * 4 + 3] * rinv);
        ((ushort4*)op)[c] = u;
    }
}

// ---------------------------------------------------------------------------
extern "C" void kernel_launch(void* const* d_in, const int* in_sizes, int n_in,
                              void* d_out, int out_size, void* d_ws, size_t ws_size,
                              hipStream_t stream)
{
    // ws layout (u16 units):
    //   qkvT : 0        .. 18874368   (36MiB)
    //   xb   : 18874368 .. 25165824   (12MiB; converted x, reused as attn out)
    //   smalls at S=25165824: qkvw(1769472) projw(589824) qkvb(2304)
    //                         projb(768) relh(4032) relw(4032)
    //   flag : int at u16 offset 27536256 (byte 55072512)
    u16* ws16  = (u16*)d_ws;
    u16* qkvT  = ws16;
    u16* xb    = ws16 + (size_t)18874368;
    u16* attn  = xb;                       // x dead after K1
    const size_t S = 25165824;
    u16* qkvw_b = ws16 + S;
    u16* projw_b = qkvw_b + 1769472;
    u16* qkvb_b = projw_b + 589824;
    u16* projb_b = qkvb_b + 2304;
    u16* relh_b = projb_b + 768;
    u16* relw_b = relh_b + 4032;
    int* flag = (int*)(ws16 + S + 2370432);

    detect_dtype<<<1, 64, 0, stream>>>((const u16*)d_in[0], flag);
    convert_in<<<6144, 256, 0, stream>>>(d_in[0], xb,      6291456, flag);
    convert_in<<<1728, 256, 0, stream>>>(d_in[1], qkvw_b,  1769472, flag);
    convert_in<<<9,    256, 0, stream>>>(d_in[2], qkvb_b,  2304,    flag);
    convert_in<<<576,  256, 0, stream>>>(d_in[3], projw_b, 589824,  flag);
    convert_in<<<3,    256, 0, stream>>>(d_in[4], projb_b, 768,     flag);
    convert_in<<<16,   256, 0, stream>>>(d_in[5], relh_b,  4032,    flag);
    convert_in<<<16,   256, 0, stream>>>(d_in[6], relw_b,  4032,    flag);

    gemm_qkv_rope<<<dim3(128, 36), 256, 0, stream>>>(xb, qkvw_b, qkvb_b, qkvT);
    flash_attn<<<dim3(96, 16), 256, 0, stream>>>(qkvT, relh_b, relw_b, attn);
    gemm_proj<<<dim3(128, 12), 256, 0, stream>>>(attn, projw_b, projb_b, d_out, flag);
}

// Round 4
// 281.249 us; speedup vs baseline: 2.9782x; 2.9782x over previous
//
#include <hip/hip_runtime.h>

// R4: MFMA-ized flash attention (R3 profile: flash_attn = 755/837us, VALUBusy
// 95%, MfmaUtil 0). QK^T, PV, and rel-pos bias all moved to 16x16x32 bf16
// MFMA. V stored transposed [bn][d][L] by the QKV-GEMM epilogue so the PV
// B-operand is k-contiguous. P round-trips LDS bf16 (wave-private). Dtype
// detect + convert pre-pass kept from R3 (fp32-storage confirmed).

typedef unsigned short u16;
typedef __attribute__((ext_vector_type(8))) __bf16 bf16x8;
typedef __attribute__((ext_vector_type(4))) float f32x4;

__device__ __forceinline__ float b2f(u16 u) {
    unsigned int i = ((unsigned int)u) << 16;
    float f; __builtin_memcpy(&f, &i, 4); return f;
}
__device__ __forceinline__ u16 f2b(float f) {
    unsigned int x; __builtin_memcpy(&x, &f, 4);
    x += 0x7fffu + ((x >> 16) & 1u);   // RTNE
    return (u16)(x >> 16);
}

#define LDT 72   // padded LDS row stride (bf16): 144B rows, 16B-aligned

// ---------------------------------------------------------------------------
// dtype detect (1 = fp32 storage) + convert-to-bf16 pre-pass
// ---------------------------------------------------------------------------
__global__ void detect_dtype(const u16* __restrict__ x, int* __restrict__ flag)
{
    if (threadIdx.x == 0 && blockIdx.x == 0) {
        float mx = 0.f;
        for (int i = 0; i < 128; i++) {
            float v = fabsf(b2f(x[i]));
            if (!(v <= 1e30f)) v = 1e30f;
            mx = fmaxf(mx, v);
        }
        *flag = (mx > 1e4f) ? 1 : 0;
    }
}

__global__ __launch_bounds__(256) void convert_in(
    const void* __restrict__ src, u16* __restrict__ dst, int n,
    const int* __restrict__ flag)
{
    const int fl = *flag;
    for (int i = blockIdx.x * 256 + threadIdx.x; i < n; i += gridDim.x * 256) {
        dst[i] = fl ? f2b(((const float*)src)[i]) : ((const u16*)src)[i];
    }
}

// ---------------------------------------------------------------------------
// K1: qkv GEMM + bias + 2D rope + k*0.125 + transpose.
// q,k -> [which][bn][l][d]; v -> [2][bn][d][l] (transposed for PV B-operand).
// ---------------------------------------------------------------------------
__global__ __launch_bounds__(256) void gemm_qkv_rope(
    const u16* __restrict__ A, const u16* __restrict__ Bw,
    const u16* __restrict__ qb, u16* __restrict__ qkvT)
{
    __shared__ u16 lA[64 * LDT];
    __shared__ u16 lB[64 * LDT];
    const int tid = threadIdx.x;
    const int m0 = blockIdx.x * 64, n0 = blockIdx.y * 64;
    const int wave = tid >> 6, lane = tid & 63;
    const int wm = (wave & 1) * 32, wn = (wave >> 1) * 32;
    const int lm = lane & 15, lq = lane >> 4;
    f32x4 acc[2][2] = {};
    for (int k0 = 0; k0 < 768; k0 += 64) {
        if (k0) __syncthreads();
        #pragma unroll
        for (int s = tid; s < 512; s += 256) {
            const int row = s >> 3, kg = (s & 7) * 8;
            *(uint4*)&lA[row * LDT + kg] = *(const uint4*)(A + (size_t)(m0 + row) * 768 + k0 + kg);
            *(uint4*)&lB[row * LDT + kg] = *(const uint4*)(Bw + (size_t)(n0 + row) * 768 + k0 + kg);
        }
        __syncthreads();
        #pragma unroll
        for (int ks = 0; ks < 64; ks += 32) {
            bf16x8 a0 = *(const bf16x8*)&lA[(wm + lm) * LDT + ks + lq * 8];
            bf16x8 a1 = *(const bf16x8*)&lA[(wm + 16 + lm) * LDT + ks + lq * 8];
            bf16x8 b0 = *(const bf16x8*)&lB[(wn + lm) * LDT + ks + lq * 8];
            bf16x8 b1 = *(const bf16x8*)&lB[(wn + 16 + lm) * LDT + ks + lq * 8];
            acc[0][0] = __builtin_amdgcn_mfma_f32_16x16x32_bf16(a0, b0, acc[0][0], 0, 0, 0);
            acc[0][1] = __builtin_amdgcn_mfma_f32_16x16x32_bf16(a0, b1, acc[0][1], 0, 0, 0);
            acc[1][0] = __builtin_amdgcn_mfma_f32_16x16x32_bf16(a1, b0, acc[1][0], 0, 0, 0);
            acc[1][1] = __builtin_amdgcn_mfma_f32_16x16x32_bf16(a1, b1, acc[1][1], 0, 0, 0);
        }
    }
    const size_t HL = (size_t)96 * 1024 * 64;
    const int which = n0 / 768;
    const int nh = (n0 >> 6) % 12;
    #pragma unroll
    for (int i = 0; i < 2; i++)
        #pragma unroll
        for (int j = 0; j < 2; j++)
            #pragma unroll
            for (int r = 0; r < 4; r++) {
                const int m = m0 + wm + i * 16 + lq * 4 + r;
                const int d = wn + j * 16 + lm;
                float v = acc[i][j][r] + b2f(qb[n0 + d]);
                const float p = __shfl_xor(v, 1);
                const int l = m & 1023, bb = m >> 10;
                float o = v;
                if (which < 2) {
                    const int pi = d >> 1, jj = pi & 15;
                    const float coord = (pi < 16) ? (float)(l & 31) : (float)(l >> 5);
                    const float ang = coord * __expf(-(float)jj * 0.5756462732485115f);
                    float sn, cs; __sincosf(ang, &sn, &cs);
                    o = v * cs + ((d & 1) ? p * sn : -(p * sn));
                    if (which == 1) o *= 0.125f;
                }
                const size_t bnl = (size_t)(bb * 12 + nh);
                size_t dst;
                if (which == 2) dst = 2 * HL + bnl * 65536 + (size_t)d * 1024 + l;  // V^T
                else            dst = (size_t)which * HL + (bnl * 1024 + l) * 64 + d;
                qkvT[dst] = f2b(o);
            }
}

// ---------------------------------------------------------------------------
// K3: proj GEMM + bias; output fp32 or bf16 per flag
// ---------------------------------------------------------------------------
__global__ __launch_bounds__(256) void gemm_proj(
    const u16* __restrict__ A, const u16* __restrict__ Bw,
    const u16* __restrict__ bias, void* __restrict__ C,
    const int* __restrict__ flag)
{
    __shared__ u16 lA[64 * LDT];
    __shared__ u16 lB[64 * LDT];
    const int tid = threadIdx.x;
    const int m0 = blockIdx.x * 64, n0 = blockIdx.y * 64;
    const int wave = tid >> 6, lane = tid & 63;
    const int wm = (wave & 1) * 32, wn = (wave >> 1) * 32;
    const int lm = lane & 15, lq = lane >> 4;
    f32x4 acc[2][2] = {};
    for (int k0 = 0; k0 < 768; k0 += 64) {
        if (k0) __syncthreads();
        #pragma unroll
        for (int s = tid; s < 512; s += 256) {
            const int row = s >> 3, kg = (s & 7) * 8;
            *(uint4*)&lA[row * LDT + kg] = *(const uint4*)(A + (size_t)(m0 + row) * 768 + k0 + kg);
            *(uint4*)&lB[row * LDT + kg] = *(const uint4*)(Bw + (size_t)(n0 + row) * 768 + k0 + kg);
        }
        __syncthreads();
        #pragma unroll
        for (int ks = 0; ks < 64; ks += 32) {
            bf16x8 a0 = *(const bf16x8*)&lA[(wm + lm) * LDT + ks + lq * 8];
            bf16x8 a1 = *(const bf16x8*)&lA[(wm + 16 + lm) * LDT + ks + lq * 8];
            bf16x8 b0 = *(const bf16x8*)&lB[(wn + lm) * LDT + ks + lq * 8];
            bf16x8 b1 = *(const bf16x8*)&lB[(wn + 16 + lm) * LDT + ks + lq * 8];
            acc[0][0] = __builtin_amdgcn_mfma_f32_16x16x32_bf16(a0, b0, acc[0][0], 0, 0, 0);
            acc[0][1] = __builtin_amdgcn_mfma_f32_16x16x32_bf16(a0, b1, acc[0][1], 0, 0, 0);
            acc[1][0] = __builtin_amdgcn_mfma_f32_16x16x32_bf16(a1, b0, acc[1][0], 0, 0, 0);
            acc[1][1] = __builtin_amdgcn_mfma_f32_16x16x32_bf16(a1, b1, acc[1][1], 0, 0, 0);
        }
    }
    const int fl = *flag;
    #pragma unroll
    for (int i = 0; i < 2; i++)
        #pragma unroll
        for (int j = 0; j < 2; j++)
            #pragma unroll
            for (int r = 0; r < 4; r++) {
                const int m = m0 + wm + i * 16 + lq * 4 + r;
                const int n = n0 + wn + j * 16 + lm;
                const float v = acc[i][j][r] + b2f(bias[n]);
                if (fl) ((float*)C)[(size_t)m * 768 + n] = v;
                else    ((u16*)C)[(size_t)m * 768 + n] = f2b(v);
            }
}

// ---------------------------------------------------------------------------
// K2: MFMA flash attention. Block = (head bn, 64-q tile), 4 waves x 16 q.
// Per k-tile (64 keys): S^T[k][q] = K·Q^T (8 MFMA), softmax (in-lane 16 +
// shfl_xor 16/32), P->LDS bf16 (wave-private), O[q][d] += P·V (8 MFMA).
// Bias via Th/Tw = Q·relH^T / Q·relW^T precomputed with MFMA once per block.
// LDS 46.1KB -> 3 blocks/CU.
// ---------------------------------------------------------------------------
__global__ __launch_bounds__(256) void flash_attn_mfma(
    const u16* __restrict__ qkvT, const u16* __restrict__ relH,
    const u16* __restrict__ relW, u16* __restrict__ outb)
{
    __shared__ char smem[46080];
    u16 (*ks2)[LDT] = (u16(*)[LDT])smem;                 // K tile [k][d]
    u16 (*vsT)[LDT] = (u16(*)[LDT])(smem + 9216);        // V^T tile [d][k]
    u16 (*rel)[LDT] = vsT;                               // alias: rel staging (prologue)
    u16 (*qs)[LDT]  = (u16(*)[LDT])(smem + 18432);       // Q tile [q][d]
    u16 (*pT)[LDT]  = qs;                                // alias: P [q][k] (loop)
    u16 (*Th)[LDT]  = (u16(*)[LDT])(smem + 27648);       // Th[q][r] bf16
    u16 (*Tw)[LDT]  = (u16(*)[LDT])(smem + 36864);       // Tw[q][r] bf16

    const int tid = threadIdx.x;
    const int bn = blockIdx.x, q0 = blockIdx.y * 64;
    const size_t HL = (size_t)96 * 1024 * 64;
    const u16* qg  = qkvT + (size_t)bn * 65536 + (size_t)q0 * 64;
    const u16* kgb = qkvT + HL + (size_t)bn * 65536;
    const u16* vTg = qkvT + 2 * HL + (size_t)bn * 65536;   // [d][1024]

    // ---- prologue: stage Q + relH ----
    for (int g = tid; g < 1024; g += 256) {
        int r = g >> 4, c = (g & 15) * 4;
        *(ushort4*)&qs[r][c] = ((const ushort4*)qg)[g];
    }
    for (int g = tid; g < 1008; g += 256) {               // relH: 63x64
        int r = g >> 4, c = (g & 15) * 4;
        *(ushort4*)&rel[r][c] = *(const ushort4*)(relH + g * 4);
    }
    if (tid < 16) { ushort4 z = {0, 0, 0, 0}; *(ushort4*)&rel[63][tid * 4] = z; }
    __syncthreads();

    const int w = tid >> 6, lane = tid & 63;
    const int lm = lane & 15, lq = lane >> 4;

    // Q fragments (wave's 16 q rows), reused as A (Th/Tw) and B (QK^T)
    const bf16x8 bq0 = *(const bf16x8*)&qs[w * 16 + lm][lq * 8];
    const bf16x8 bq1 = *(const bf16x8*)&qs[w * 16 + lm][32 + lq * 8];

    // Th = Q . relH^T
    {
        f32x4 tacc[4] = {};
        #pragma unroll
        for (int nb = 0; nb < 4; nb++) {
            bf16x8 r0 = *(const bf16x8*)&rel[nb * 16 + lm][lq * 8];
            bf16x8 r1 = *(const bf16x8*)&rel[nb * 16 + lm][32 + lq * 8];
            tacc[nb] = __builtin_amdgcn_mfma_f32_16x16x32_bf16(bq0, r0, tacc[nb], 0, 0, 0);
            tacc[nb] = __builtin_amdgcn_mfma_f32_16x16x32_bf16(bq1, r1, tacc[nb], 0, 0, 0);
        }
        #pragma unroll
        for (int nb = 0; nb < 4; nb++)
            #pragma unroll
            for (int rr = 0; rr < 4; rr++)
                Th[w * 16 + lq * 4 + rr][nb * 16 + lm] = f2b(tacc[nb][rr]);
    }
    __syncthreads();                                      // rel buffer free
    for (int g = tid; g < 1008; g += 256) {               // relW: 63x64
        int r = g >> 4, c = (g & 15) * 4;
        *(ushort4*)&rel[r][c] = *(const ushort4*)(relW + g * 4);
    }
    if (tid < 16) { ushort4 z = {0, 0, 0, 0}; *(ushort4*)&rel[63][tid * 4] = z; }
    __syncthreads();
    {
        f32x4 tacc[4] = {};
        #pragma unroll
        for (int nb = 0; nb < 4; nb++) {
            bf16x8 r0 = *(const bf16x8*)&rel[nb * 16 + lm][lq * 8];
            bf16x8 r1 = *(const bf16x8*)&rel[nb * 16 + lm][32 + lq * 8];
            tacc[nb] = __builtin_amdgcn_mfma_f32_16x16x32_bf16(bq0, r0, tacc[nb], 0, 0, 0);
            tacc[nb] = __builtin_amdgcn_mfma_f32_16x16x32_bf16(bq1, r1, tacc[nb], 0, 0, 0);
        }
        #pragma unroll
        for (int nb = 0; nb < 4; nb++)
            #pragma unroll
            for (int rr = 0; rr < 4; rr++)
                Tw[w * 16 + lq * 4 + rr][nb * 16 + lm] = f2b(tacc[nb][rr]);
    }
    // hoisted w-bias: kw = (mb&1)*16 + lq*4 + rr, qw = (w&1)*16 + lm
    const int qw = (w & 1) * 16 + lm;
    float rw_l[8];
    #pragma unroll
    for (int mb2 = 0; mb2 < 2; mb2++)
        #pragma unroll
        for (int rr = 0; rr < 4; rr++) {
            const int kw = mb2 * 16 + lq * 4 + rr;
            rw_l[mb2 * 4 + rr] = b2f(Tw[w * 16 + lm][qw - kw + 31]);
        }
    const int qh = (q0 >> 5) + (w >= 2 ? 1 : 0);

    float m_run = -1e30f, l_run = 0.f;
    f32x4 oacc[4] = {};

    #pragma unroll 1
    for (int kt = 0; kt < 16; kt++) {
        __syncthreads();                                   // prior readers done
        const u16* kp = kgb + (size_t)kt * 4096;
        for (int g = tid; g < 1024; g += 256) {
            int r = g >> 4, c = (g & 15) * 4;
            *(ushort4*)&ks2[r][c] = ((const ushort4*)kp)[g];
            *(ushort4*)&vsT[r][c] = *(const ushort4*)(vTg + (size_t)r * 1024 + kt * 64 + c);
        }
        __syncthreads();
        // S^T[k][q]: A = K rows, B = Q rows
        f32x4 sacc[4];
        #pragma unroll
        for (int mb = 0; mb < 4; mb++) {
            bf16x8 ka0 = *(const bf16x8*)&ks2[mb * 16 + lm][lq * 8];
            bf16x8 ka1 = *(const bf16x8*)&ks2[mb * 16 + lm][32 + lq * 8];
            f32x4 s = {};
            s = __builtin_amdgcn_mfma_f32_16x16x32_bf16(ka0, bq0, s, 0, 0, 0);
            s = __builtin_amdgcn_mfma_f32_16x16x32_bf16(ka1, bq1, s, 0, 0, 0);
            sacc[mb] = s;
        }
        const float rh0 = b2f(Th[w * 16 + lm][qh - 2 * kt + 31]);   // klocal < 32
        const float rh1 = b2f(Th[w * 16 + lm][qh - 2 * kt + 30]);   // klocal >= 32
        float sc[16];
        #pragma unroll
        for (int mb = 0; mb < 4; mb++)
            #pragma unroll
            for (int rr = 0; rr < 4; rr++)
                sc[mb * 4 + rr] = sacc[mb][rr] + (mb >= 2 ? rh1 : rh0) + rw_l[(mb & 1) * 4 + rr];
        float tmax = sc[0];
        #pragma unroll
        for (int j = 1; j < 16; j++) tmax = fmaxf(tmax, sc[j]);
        tmax = fmaxf(tmax, __shfl_xor(tmax, 16));
        tmax = fmaxf(tmax, __shfl_xor(tmax, 32));
        const float m_new = fmaxf(m_run, tmax);
        const float alpha = __expf(m_run - m_new);
        float lsum = 0.f;
        #pragma unroll
        for (int j = 0; j < 16; j++) { float pv = __expf(sc[j] - m_new); sc[j] = pv; lsum += pv; }
        lsum += __shfl_xor(lsum, 16);
        lsum += __shfl_xor(lsum, 32);
        m_run = m_new;
        l_run = l_run * alpha + lsum;
        // P -> LDS (wave-private rows w*16..w*16+15)
        #pragma unroll
        for (int mb = 0; mb < 4; mb++) {
            unsigned int lo = (unsigned)f2b(sc[mb * 4 + 0]) | ((unsigned)f2b(sc[mb * 4 + 1]) << 16);
            unsigned int hi = (unsigned)f2b(sc[mb * 4 + 2]) | ((unsigned)f2b(sc[mb * 4 + 3]) << 16);
            uint2 u = {lo, hi};
            *(uint2*)&pT[w * 16 + lm][mb * 16 + lq * 4] = u;
        }
        // rescale O rows (row q' = lq*4+rr in C-layout; alpha keyed by lane&15)
        float al[4];
        #pragma unroll
        for (int rr = 0; rr < 4; rr++) al[rr] = __shfl(alpha, lq * 4 + rr);
        #pragma unroll
        for (int nb = 0; nb < 4; nb++)
            #pragma unroll
            for (int rr = 0; rr < 4; rr++) oacc[nb][rr] *= al[rr];
        // O += P . V  (A = P rows, B = V^T rows)
        const bf16x8 pa0 = *(const bf16x8*)&pT[w * 16 + lm][lq * 8];
        const bf16x8 pa1 = *(const bf16x8*)&pT[w * 16 + lm][32 + lq * 8];
        #pragma unroll
        for (int nb = 0; nb < 4; nb++) {
            bf16x8 vb0 = *(const bf16x8*)&vsT[nb * 16 + lm][lq * 8];
            bf16x8 vb1 = *(const bf16x8*)&vsT[nb * 16 + lm][32 + lq * 8];
            oacc[nb] = __builtin_amdgcn_mfma_f32_16x16x32_bf16(pa0, vb0, oacc[nb], 0, 0, 0);
            oacc[nb] = __builtin_amdgcn_mfma_f32_16x16x32_bf16(pa1, vb1, oacc[nb], 0, 0, 0);
        }
    }
    const float rinv = 1.f / l_run;
    float rv[4];
    #pragma unroll
    for (int rr = 0; rr < 4; rr++) rv[rr] = __shfl(rinv, lq * 4 + rr);
    const int bb = bn / 12, nh = bn % 12;
    #pragma unroll
    for (int nb = 0; nb < 4; nb++)
        #pragma unroll
        for (int rr = 0; rr < 4; rr++) {
            const int qrow = q0 + w * 16 + lq * 4 + rr;
            const int d = nb * 16 + lm;
            outb[((size_t)(bb * 1024 + qrow)) * 768 + nh * 64 + d] = f2b(oacc[nb][rr] * rv[rr]);
        }
}

// ---------------------------------------------------------------------------
extern "C" void kernel_launch(void* const* d_in, const int* in_sizes, int n_in,
                              void* d_out, int out_size, void* d_ws, size_t ws_size,
                              hipStream_t stream)
{
    u16* ws16  = (u16*)d_ws;
    u16* qkvT  = ws16;
    u16* xb    = ws16 + (size_t)18874368;
    u16* attn  = xb;                       // x dead after K1
    const size_t S = 25165824;
    u16* qkvw_b = ws16 + S;
    u16* projw_b = qkvw_b + 1769472;
    u16* qkvb_b = projw_b + 589824;
    u16* projb_b = qkvb_b + 2304;
    u16* relh_b = projb_b + 768;
    u16* relw_b = relh_b + 4032;
    int* flag = (int*)(ws16 + S + 2370432);

    detect_dtype<<<1, 64, 0, stream>>>((const u16*)d_in[0], flag);
    convert_in<<<6144, 256, 0, stream>>>(d_in[0], xb,      6291456, flag);
    convert_in<<<1728, 256, 0, stream>>>(d_in[1], qkvw_b,  1769472, flag);
    convert_in<<<9,    256, 0, stream>>>(d_in[2], qkvb_b,  2304,    flag);
    convert_in<<<576,  256, 0, stream>>>(d_in[3], projw_b, 589824,  flag);
    convert_in<<<3,    256, 0, stream>>>(d_in[4], projb_b, 768,     flag);
    convert_in<<<16,   256, 0, stream>>>(d_in[5], relh_b,  4032,    flag);
    convert_in<<<16,   256, 0, stream>>>(d_in[6], relw_b,  4032,    flag);

    gemm_qkv_rope<<<dim3(128, 36), 256, 0, stream>>>(xb, qkvw_b, qkvb_b, qkvT);
    flash_attn_mfma<<<dim3(96, 16), 256, 0, stream>>>(qkvT, relh_b, relw_b, attn);
    gemm_proj<<<dim3(128, 12), 256, 0, stream>>>(attn, projw_b, projb_b, d_out, flag);
}